// Round 3
// baseline (469.185 us; speedup 1.0000x reference)
//
#include <hip/hip_runtime.h>
#include <hip/hip_bf16.h>
#include <math.h>

// MoE: 8 experts, top-2, H=1024, I=4096, T=2048. f32 in/out, bf16 MFMA inside.
// Round 3: M=128 tiles, 8 waves, double-buffered LDS with prefetch-before-MFMA
// (T3-minimum 2-phase), one barrier per K-step.
constexpr int kNE = 8;
constexpr int kH  = 1024;
constexpr int kI  = 4096;
constexpr int kT  = 2048;
constexpr int kMaxSlots = kT * 2 + kNE * 64;   // 4608 (segments padded to 64)
constexpr int kSlotPad  = kMaxSlots + 128;     // slot arrays padded for M=128 reads

typedef short bf16x8 __attribute__((ext_vector_type(8)));
typedef float f32x4  __attribute__((ext_vector_type(4)));

__device__ __forceinline__ short f2bf(float f) {
  union { float f; unsigned u; } v; v.f = f;
  unsigned r = v.u + 0x7fffu + ((v.u >> 16) & 1u);   // RNE
  return (short)(r >> 16);
}

__device__ __forceinline__ void gload16(const void* g, void* lds) {
  __builtin_amdgcn_global_load_lds(
      (const __attribute__((address_space(1))) void*)g,
      (__attribute__((address_space(3))) void*)lds, 16, 0, 0);
}

// ---------------- router: logits, top-2, renormalized weights ----------------
__global__ __launch_bounds__(256) void router_kernel(
    const float* __restrict__ hs, const float* __restrict__ gw,
    int* __restrict__ cnt, int* __restrict__ tok_e, float* __restrict__ tok_w) {
  const int lane = threadIdx.x & 63;
  const int wid  = threadIdx.x >> 6;
  const int t = blockIdx.x * 4 + wid;
  const float* hrow = hs + (size_t)t * kH;
  float acc[kNE];
#pragma unroll
  for (int e = 0; e < kNE; ++e) acc[e] = 0.f;
  for (int i = lane; i < kH; i += 64) {
    float x = hrow[i];
    float4 g0 = *(const float4*)(gw + (size_t)i * kNE);
    float4 g1 = *(const float4*)(gw + (size_t)i * kNE + 4);
    acc[0] += x * g0.x; acc[1] += x * g0.y; acc[2] += x * g0.z; acc[3] += x * g0.w;
    acc[4] += x * g1.x; acc[5] += x * g1.y; acc[6] += x * g1.z; acc[7] += x * g1.w;
  }
#pragma unroll
  for (int o = 32; o; o >>= 1)
#pragma unroll
    for (int e = 0; e < kNE; ++e) acc[e] += __shfl_xor(acc[e], o);
  if (lane == 0) {
    int e0 = 0;
#pragma unroll
    for (int e = 1; e < kNE; ++e) if (acc[e] > acc[e0]) e0 = e;
    int e1 = (e0 == 0) ? 1 : 0;
#pragma unroll
    for (int e = 0; e < kNE; ++e) if (e != e0 && acc[e] > acc[e1]) e1 = e;
    float d  = acc[e1] - acc[e0];                 // <= 0
    float w0 = 1.f / (1.f + expf(d));
    float w1 = 1.f / (1.f + expf(-d));
    atomicAdd(&cnt[e0], 1);
    atomicAdd(&cnt[e1], 1);
    tok_e[t * 2] = e0; tok_e[t * 2 + 1] = e1;
    tok_w[t * 2] = w0; tok_w[t * 2 + 1] = w1;
  }
}

// ------------- segment offsets (padded to 64) + slot-array init --------------
__global__ __launch_bounds__(256) void offsets_kernel(
    const int* __restrict__ cnt, int* __restrict__ off,
    int* __restrict__ slot_token, float* __restrict__ slot_weight) {
  if (threadIdx.x == 0) {
    int o = 0;
#pragma unroll
    for (int e = 0; e < kNE; ++e) { off[e] = o; o += (cnt[e] + 63) & ~63; }
    off[kNE] = o;
  }
  for (int i = threadIdx.x; i < kSlotPad; i += 256) {
    slot_token[i]  = -1;
    slot_weight[i] = 0.f;
  }
}

// ---------------- scatter tokens into expert slot segments ------------------
__global__ __launch_bounds__(256) void assign_kernel(
    const int* __restrict__ tok_e, const float* __restrict__ tok_w,
    const int* __restrict__ off, int* __restrict__ cursor,
    int* __restrict__ slot_token, float* __restrict__ slot_weight,
    int* __restrict__ token_slots) {
  const int t = blockIdx.x * 256 + threadIdx.x;
  if (t >= kT) return;
#pragma unroll
  for (int k = 0; k < 2; ++k) {
    int e = tok_e[t * 2 + k];
    int pos = off[e] + atomicAdd(&cursor[e], 1);
    slot_token[pos]  = t;
    slot_weight[pos] = tok_w[t * 2 + k];
    token_slots[t * 2 + k] = pos;
  }
}

// ------------------- hs f32 -> bf16 (row-major, unchanged) ------------------
__global__ __launch_bounds__(256) void conv_hs_kernel(
    const float* __restrict__ hs, short* __restrict__ hsb) {
  const int idx = blockIdx.x * 256 + threadIdx.x;     // 8 elems each
  const float* p = hs + (size_t)idx * 8;
  float4 a = *(const float4*)p;
  float4 b = *(const float4*)(p + 4);
  bf16x8 w;
  w[0] = f2bf(a.x); w[1] = f2bf(a.y); w[2] = f2bf(a.z); w[3] = f2bf(a.w);
  w[4] = f2bf(b.x); w[5] = f2bf(b.y); w[6] = f2bf(b.z); w[7] = f2bf(b.w);
  *(bf16x8*)(hsb + (size_t)idx * 8) = w;
}

// ------- weight transpose+convert: f32 [E][K][N] -> bf16 [E][N][K] ----------
// z encodes (which tensor, expert): e = z&7, sel = z>>3.
__global__ __launch_bounds__(256) void tconv13_kernel(
    const float* __restrict__ w1s, const float* __restrict__ w3s,
    short* __restrict__ w1t, short* __restrict__ w3t) {
  __shared__ float tile[64][65];
  const int z = blockIdx.z;
  const int e = z & 7, sel = z >> 3;
  const int K = kH, N = kI;
  const float* src = (sel ? w3s : w1s) + (size_t)e * K * N;
  short* dst = (sel ? w3t : w1t) + (size_t)e * K * N;
  const int n0 = blockIdx.x * 64, k0 = blockIdx.y * 64;
  const int tid = threadIdx.x;
  const int tn = (tid & 15) * 4, tk = tid >> 4;
#pragma unroll
  for (int i = 0; i < 4; ++i) {
    float4 v = *(const float4*)(src + (size_t)(k0 + tk + i * 16) * N + n0 + tn);
    tile[tk + i * 16][tn] = v.x; tile[tk + i * 16][tn + 1] = v.y;
    tile[tk + i * 16][tn + 2] = v.z; tile[tk + i * 16][tn + 3] = v.w;
  }
  __syncthreads();
  const int kc = tid & 7;
#pragma unroll
  for (int i = 0; i < 2; ++i) {
    int n = (tid >> 3) + i * 32;
    bf16x8 w;
#pragma unroll
    for (int j = 0; j < 8; ++j) w[j] = f2bf(tile[kc * 8 + j][n]);
    *(bf16x8*)(dst + (size_t)(n0 + n) * K + k0 + kc * 8) = w;
  }
}

__global__ __launch_bounds__(256) void tconv_kernel(
    const float* __restrict__ src0, short* __restrict__ dst0, int K, int N) {
  __shared__ float tile[64][65];
  const int e = blockIdx.z;
  const float* src = src0 + (size_t)e * K * N;
  short* dst = dst0 + (size_t)e * K * N;
  const int n0 = blockIdx.x * 64, k0 = blockIdx.y * 64;
  const int tid = threadIdx.x;
  const int tn = (tid & 15) * 4, tk = tid >> 4;
#pragma unroll
  for (int i = 0; i < 4; ++i) {
    float4 v = *(const float4*)(src + (size_t)(k0 + tk + i * 16) * N + n0 + tn);
    tile[tk + i * 16][tn] = v.x; tile[tk + i * 16][tn + 1] = v.y;
    tile[tk + i * 16][tn + 2] = v.z; tile[tk + i * 16][tn + 3] = v.w;
  }
  __syncthreads();
  const int kc = tid & 7;
#pragma unroll
  for (int i = 0; i < 2; ++i) {
    int n = (tid >> 3) + i * 32;
    bf16x8 w;
#pragma unroll
    for (int j = 0; j < 8; ++j) w[j] = f2bf(tile[kc * 8 + j][n]);
    *(bf16x8*)(dst + (size_t)(n0 + n) * K + k0 + kc * 8) = w;
  }
}

// --------- GEMM1: inter[slot] = silu(x@w1) * (x@w3), bf16 out ---------------
// 128m x 128n, BK=64, 8 waves (4x2), dbuf LDS + prefetch, 1 barrier/step.
__global__ __launch_bounds__(512, 2) void g1_kernel(
    const short* __restrict__ hsb,
    const short* __restrict__ w1t, const short* __restrict__ w3t,
    const int* __restrict__ cnt, const int* __restrict__ off,
    const int* __restrict__ slot_token, short* __restrict__ inter) {
  const int e = blockIdx.z;
  const int count = cnt[e];
  const int rb = blockIdx.y;
  if (rb * 128 >= count) return;
  const int slot0 = off[e] + rb * 128;
  const int mlim = ((count + 63) & ~63) - rb * 128;   // valid rows this block
  const int nb = blockIdx.x * 128;

  __shared__ __align__(16) short As[2][8 * 128 * 8];    // 16KB x2  [kc][m][8]
  __shared__ __align__(16) short Bs[2][2 * 128 * 64];   // 32KB x2  [s][n][kcs][8]

  const int tid = threadIdx.x;
  const int l = tid & 63, w = tid >> 6;

  // ---- A staging map: thread -> (m, kc0) and (m, kc0+4) ----
  const int am = (w & 1) * 64 + l;       // m 0..127
  const int kc0 = w >> 1;                // 0..3
  int tok = slot_token[slot0 + am]; if (tok < 0) tok = 0;
  const short* arow = hsb + (size_t)tok * kH;
  const unsigned adst0 = (unsigned)((kc0 * 128 + am) * 16);
  const unsigned adst1 = (unsigned)(((kc0 + 4) * 128 + am) * 16);

  // ---- B staging map (source-side XOR swizzle on k-chunk) ----
  const int nrl = l >> 3;
  const int ksw = ((l & 7) ^ nrl) * 8;
  const short* bsrc[4];
  unsigned bdst[4];
#pragma unroll
  for (int i = 0; i < 4; ++i) {
    const int s = i >> 1;
    const int nB = (i & 1) * 64 + w * 8 + nrl;
    const short* wt = (s ? w3t : w1t) + (size_t)e * kH * kI;
    bsrc[i] = wt + (size_t)(nb + nB) * kH + ksw;
    bdst[i] = (unsigned)(s * 16384 + ((i & 1) * 64 + w * 8) * 128 + l * 16);
  }

  const int wr = w >> 1, wc = w & 1;
  const int g = l >> 4, r16 = l & 15;

  f32x4 acc[2][2][4];
#pragma unroll
  for (int s = 0; s < 2; ++s)
#pragma unroll
    for (int mi = 0; mi < 2; ++mi)
#pragma unroll
      for (int ni = 0; ni < 4; ++ni)
#pragma unroll
        for (int r = 0; r < 4; ++r) acc[s][mi][ni][r] = 0.f;

#define STAGE1(buf, k0s)                                                  \
  do {                                                                    \
    gload16(arow + (k0s) + kc0 * 8, (char*)As[buf] + adst0);              \
    gload16(arow + (k0s) + (kc0 + 4) * 8, (char*)As[buf] + adst1);        \
    _Pragma("unroll")                                                     \
    for (int i_ = 0; i_ < 4; ++i_)                                        \
      gload16(bsrc[i_] + (k0s), (char*)Bs[buf] + bdst[i_]);               \
  } while (0)

  STAGE1(0, 0);
  __syncthreads();
  for (int t = 0; t < kH / 64; ++t) {
    const int b = t & 1;
    if (t + 1 < kH / 64) STAGE1(b ^ 1, (t + 1) * 64);
#pragma unroll
    for (int kk = 0; kk < 2; ++kk) {
      const int kc = kk * 4 + g;
      bf16x8 af[2], bfr[2][4];
#pragma unroll
      for (int mi = 0; mi < 2; ++mi)
        af[mi] = *(const bf16x8*)((const char*)As[b] +
                   (kc * 128 + wr * 32 + mi * 16 + r16) * 16);
#pragma unroll
      for (int s = 0; s < 2; ++s)
#pragma unroll
        for (int ni = 0; ni < 4; ++ni) {
          const int n = wc * 64 + ni * 16 + r16;
          bfr[s][ni] = *(const bf16x8*)((const char*)Bs[b] +
                        s * 16384 + n * 128 + ((kc ^ (n & 7)) * 16));
        }
#pragma unroll
      for (int s = 0; s < 2; ++s)
#pragma unroll
        for (int mi = 0; mi < 2; ++mi)
#pragma unroll
          for (int ni = 0; ni < 4; ++ni)
            acc[s][mi][ni] = __builtin_amdgcn_mfma_f32_16x16x32_bf16(
                af[mi], bfr[s][ni], acc[s][mi][ni], 0, 0, 0);
    }
    __syncthreads();
  }
#undef STAGE1

#pragma unroll
  for (int mi = 0; mi < 2; ++mi)
#pragma unroll
    for (int r = 0; r < 4; ++r) {
      const int m = wr * 32 + mi * 16 + g * 4 + r;
      if (m < mlim) {
#pragma unroll
        for (int ni = 0; ni < 4; ++ni) {
          float h1 = acc[0][mi][ni][r];
          float h3 = acc[1][mi][ni][r];
          float y = h1 / (1.f + expf(-h1)) * h3;
          inter[(size_t)(slot0 + m) * kI + nb + wc * 64 + ni * 16 + r16] = f2bf(y);
        }
      }
    }
}

// --------- GEMM2: slot_out = w_slot * (inter @ w2), split-K=2 ---------------
// 128m x 128n, BK=64, 8 waves, dbuf + prefetch.
__global__ __launch_bounds__(512, 4) void g2_kernel(
    const short* __restrict__ inter, const short* __restrict__ w2t,
    const int* __restrict__ cnt, const int* __restrict__ off,
    const float* __restrict__ slot_weight, float* __restrict__ slot_out) {
  const int zz = blockIdx.z;
  const int e = zz & 7, half = zz >> 3;
  const int count = cnt[e];
  const int rb = blockIdx.y;
  if (rb * 128 >= count) return;
  const int slot0 = off[e] + rb * 128;
  const int mlim = ((count + 63) & ~63) - rb * 128;
  const int nb = blockIdx.x * 128;
  const int kbase = half * (kI / 2);

  __shared__ __align__(16) short As[2][8 * 128 * 8];    // 16KB x2
  __shared__ __align__(16) short Bs[2][128 * 64];       // 16KB x2

  const int tid = threadIdx.x;
  const int l = tid & 63, w = tid >> 6;

  const int am = (w & 1) * 64 + l;
  const int kc0 = w >> 1;
  int slot_r = slot0 + am;
  if (slot_r >= kMaxSlots) slot_r = kMaxSlots - 1;      // clamp: rows discarded
  const short* arow = inter + (size_t)slot_r * kI + kbase;
  const unsigned adst0 = (unsigned)((kc0 * 128 + am) * 16);
  const unsigned adst1 = (unsigned)(((kc0 + 4) * 128 + am) * 16);

  const int nrl = l >> 3;
  const int ksw = ((l & 7) ^ nrl) * 8;
  const short* bsrc[2];
  unsigned bdst[2];
#pragma unroll
  for (int i = 0; i < 2; ++i) {
    const int nB = i * 64 + w * 8 + nrl;
    bsrc[i] = w2t + (size_t)e * kI * kH + (size_t)(nb + nB) * kI + kbase + ksw;
    bdst[i] = (unsigned)((i * 64 + w * 8) * 128 + l * 16);
  }

  const int wr = w >> 1, wc = w & 1;
  const int g = l >> 4, r16 = l & 15;

  f32x4 acc[2][4];
#pragma unroll
  for (int mi = 0; mi < 2; ++mi)
#pragma unroll
    for (int ni = 0; ni < 4; ++ni)
#pragma unroll
      for (int r = 0; r < 4; ++r) acc[mi][ni][r] = 0.f;

#define STAGE2(buf, k0s)                                                  \
  do {                                                                    \
    gload16(arow + (k0s) + kc0 * 8, (char*)As[buf] + adst0);              \
    gload16(arow + (k0s) + (kc0 + 4) * 8, (char*)As[buf] + adst1);        \
    gload16(bsrc[0] + (k0s), (char*)Bs[buf] + bdst[0]);                   \
    gload16(bsrc[1] + (k0s), (char*)Bs[buf] + bdst[1]);                   \
  } while (0)

  STAGE2(0, 0);
  __syncthreads();
  for (int t = 0; t < (kI / 2) / 64; ++t) {
    const int b = t & 1;
    if (t + 1 < (kI / 2) / 64) STAGE2(b ^ 1, (t + 1) * 64);
#pragma unroll
    for (int kk = 0; kk < 2; ++kk) {
      const int kc = kk * 4 + g;
      bf16x8 af[2], bfr[4];
#pragma unroll
      for (int mi = 0; mi < 2; ++mi)
        af[mi] = *(const bf16x8*)((const char*)As[b] +
                   (kc * 128 + wr * 32 + mi * 16 + r16) * 16);
#pragma unroll
      for (int ni = 0; ni < 4; ++ni) {
        const int n = wc * 64 + ni * 16 + r16;
        bfr[ni] = *(const bf16x8*)((const char*)Bs[b] +
                    n * 128 + ((kc ^ (n & 7)) * 16));
      }
#pragma unroll
      for (int mi = 0; mi < 2; ++mi)
#pragma unroll
        for (int ni = 0; ni < 4; ++ni)
          acc[mi][ni] = __builtin_amdgcn_mfma_f32_16x16x32_bf16(
              af[mi], bfr[ni], acc[mi][ni], 0, 0, 0);
    }
    __syncthreads();
  }
#undef STAGE2

#pragma unroll
  for (int mi = 0; mi < 2; ++mi)
#pragma unroll
    for (int r = 0; r < 4; ++r) {
      const int m = wr * 32 + mi * 16 + g * 4 + r;
      if (m < mlim) {
        const float sw = slot_weight[slot0 + m];
#pragma unroll
        for (int ni = 0; ni < 4; ++ni)
          slot_out[((size_t)half * kMaxSlots + slot0 + m) * kH +
                   nb + wc * 64 + ni * 16 + r16] = sw * acc[mi][ni][r];
      }
    }
}

// ------- combine: out[t] = sum over 2 slots x 2 K-halves of slot_out --------
__global__ __launch_bounds__(256) void combine4_kernel(
    const float* __restrict__ slot_out, const int* __restrict__ token_slots,
    float* __restrict__ out) {
  int idx = blockIdx.x * 256 + threadIdx.x;
  int t = idx >> 8;
  int c = (idx & 255) * 4;
  int s0 = token_slots[t * 2];
  int s1 = token_slots[t * 2 + 1];
  const size_t HS = (size_t)kMaxSlots * kH;
  float4 a = *(const float4*)(slot_out + (size_t)s0 * kH + c);
  float4 b = *(const float4*)(slot_out + (size_t)s1 * kH + c);
  float4 a2 = *(const float4*)(slot_out + HS + (size_t)s0 * kH + c);
  float4 b2 = *(const float4*)(slot_out + HS + (size_t)s1 * kH + c);
  float4 o;
  o.x = a.x + b.x + a2.x + b2.x; o.y = a.y + b.y + a2.y + b2.y;
  o.z = a.z + b.z + a2.z + b2.z; o.w = a.w + b.w + a2.w + b2.w;
  *(float4*)(out + (size_t)t * kH + c) = o;
}

// ===================== fallback path (r1, in-loop convert) ==================
__global__ __launch_bounds__(256) void fb_mlp1(
    const float* __restrict__ hs,
    const float* __restrict__ w1s, const float* __restrict__ w3s,
    const int* __restrict__ cnt, const int* __restrict__ off,
    const int* __restrict__ slot_token, short* __restrict__ inter) {
  const int e = blockIdx.z;
  const int count = cnt[e];
  const int rb = blockIdx.y;
  if (rb * 64 >= count) return;
  const int slot0 = off[e] + rb * 64;
  const int nb = blockIdx.x * 128;
  __shared__ __align__(16) short As[4 * 64 * 8];
  __shared__ __align__(16) short Bs[2][4 * 128 * 8];
  const int tid  = threadIdx.x;
  const int lane = tid & 63;
  const int wid  = tid >> 6;
  const int wr = wid >> 1, wc = wid & 1;
  const int am = tid & 63, akb = tid >> 6;
  int tok = slot_token[slot0 + am];
  if (tok < 0) tok = 0;
  const float* arow = hs + (size_t)tok * kH + akb * 8;
  const int which = tid >> 7;
  const int bn0 = (tid & 31) * 4;
  const int bkb = (tid >> 5) & 3;
  const float* wbase = (which ? w3s : w1s) +
      (size_t)e * kH * kI + (size_t)(bkb * 8) * kI + nb + bn0;
  char* bdstp = (char*)&Bs[which][0];
  f32x4 acc[2][2][4];
#pragma unroll
  for (int s = 0; s < 2; ++s)
#pragma unroll
    for (int mi = 0; mi < 2; ++mi)
#pragma unroll
      for (int ni = 0; ni < 4; ++ni)
#pragma unroll
        for (int r = 0; r < 4; ++r) acc[s][mi][ni][r] = 0.f;
  const int g = lane >> 4, r16 = lane & 15;
  for (int k0 = 0; k0 < kH; k0 += 32) {
    float4 a0 = *(const float4*)(arow + k0);
    float4 a1 = *(const float4*)(arow + k0 + 4);
    bf16x8 av;
    av[0] = f2bf(a0.x); av[1] = f2bf(a0.y); av[2] = f2bf(a0.z); av[3] = f2bf(a0.w);
    av[4] = f2bf(a1.x); av[5] = f2bf(a1.y); av[6] = f2bf(a1.z); av[7] = f2bf(a1.w);
    *(bf16x8*)&As[(akb * 64 + am) * 8] = av;
    {
      const float* bp = wbase + (size_t)k0 * kI;
      float4 v[8];
#pragma unroll
      for (int j = 0; j < 8; ++j) v[j] = *(const float4*)(bp + (size_t)j * kI);
      const float* vf = (const float*)v;
#pragma unroll
      for (int i = 0; i < 4; ++i) {
        bf16x8 w;
#pragma unroll
        for (int j = 0; j < 8; ++j) w[j] = f2bf(vf[j * 4 + i]);
        int n = bn0 + i;
        unsigned ba = (unsigned)((bkb * 128 + n) * 16) ^ ((((unsigned)n >> 3) & 7u) << 4);
        *(bf16x8*)(bdstp + ba) = w;
      }
    }
    __syncthreads();
    bf16x8 af[2], bfr[2][4];
#pragma unroll
    for (int mi = 0; mi < 2; ++mi)
      af[mi] = *(const bf16x8*)&As[(g * 64 + wr * 32 + mi * 16 + r16) * 8];
#pragma unroll
    for (int s = 0; s < 2; ++s)
#pragma unroll
      for (int ni = 0; ni < 4; ++ni) {
        int n = wc * 64 + ni * 16 + r16;
        unsigned ba = (unsigned)((g * 128 + n) * 16) ^ ((((unsigned)n >> 3) & 7u) << 4);
        bfr[s][ni] = *(const bf16x8*)((char*)&Bs[s][0] + ba);
      }
#pragma unroll
    for (int s = 0; s < 2; ++s)
#pragma unroll
      for (int mi = 0; mi < 2; ++mi)
#pragma unroll
        for (int ni = 0; ni < 4; ++ni)
          acc[s][mi][ni] = __builtin_amdgcn_mfma_f32_16x16x32_bf16(
              af[mi], bfr[s][ni], acc[s][mi][ni], 0, 0, 0);
    __syncthreads();
  }
#pragma unroll
  for (int mi = 0; mi < 2; ++mi)
#pragma unroll
    for (int ni = 0; ni < 4; ++ni)
#pragma unroll
      for (int r = 0; r < 4; ++r) {
        float h1 = acc[0][mi][ni][r];
        float h3 = acc[1][mi][ni][r];
        float y = h1 / (1.f + expf(-h1)) * h3;
        int m = wr * 32 + mi * 16 + g * 4 + r;
        int n = nb + wc * 64 + ni * 16 + r16;
        inter[(size_t)(slot0 + m) * kI + n] = f2bf(y);
      }
}

__global__ __launch_bounds__(256) void fb_mlp2(
    const short* __restrict__ inter, const float* __restrict__ w2s,
    const int* __restrict__ cnt, const int* __restrict__ off,
    const float* __restrict__ slot_weight, float* __restrict__ slot_out) {
  const int e = blockIdx.z;
  const int count = cnt[e];
  const int rb = blockIdx.y;
  if (rb * 64 >= count) return;
  const int slot0 = off[e] + rb * 64;
  const int nb = blockIdx.x * 128;
  __shared__ __align__(16) short As[8 * 64 * 8];
  __shared__ __align__(16) short Bs[8 * 128 * 8];
  const int tid  = threadIdx.x;
  const int lane = tid & 63;
  const int wid  = tid >> 6;
  const int wr = wid >> 1, wc = wid & 1;
  const int am = tid & 63, akb = tid >> 6;
  const short* arow = inter + (size_t)(slot0 + am) * kI;
  const int bn0 = (tid & 31) * 4;
  const int bkb = tid >> 5;
  const float* wbase = w2s + (size_t)e * kI * kH + (size_t)(bkb * 8) * kH + nb + bn0;
  f32x4 acc[2][4];
#pragma unroll
  for (int mi = 0; mi < 2; ++mi)
#pragma unroll
    for (int ni = 0; ni < 4; ++ni)
#pragma unroll
      for (int r = 0; r < 4; ++r) acc[mi][ni][r] = 0.f;
  const int g = lane >> 4, r16 = lane & 15;
  for (int k0 = 0; k0 < kI; k0 += 64) {
    bf16x8 x0 = *(const bf16x8*)(arow + k0 + akb * 8);
    bf16x8 x1 = *(const bf16x8*)(arow + k0 + (akb + 4) * 8);
    *(bf16x8*)&As[(akb * 64 + am) * 8] = x0;
    *(bf16x8*)&As[((akb + 4) * 64 + am) * 8] = x1;
    {
      const float* bp = wbase + (size_t)k0 * kH;
      float4 v[8];
#pragma unroll
      for (int j = 0; j < 8; ++j) v[j] = *(const float4*)(bp + (size_t)j * kH);
      const float* vf = (const float*)v;
#pragma unroll
      for (int i = 0; i < 4; ++i) {
        bf16x8 w;
#pragma unroll
        for (int j = 0; j < 8; ++j) w[j] = f2bf(vf[j * 4 + i]);
        int n = bn0 + i;
        unsigned ba = (unsigned)((bkb * 128 + n) * 16) ^ ((((unsigned)n >> 3) & 7u) << 4);
        *(bf16x8*)((char*)&Bs[0] + ba) = w;
      }
    }
    __syncthreads();
#pragma unroll
    for (int kk = 0; kk < 2; ++kk) {
      bf16x8 af[2], bfr[4];
#pragma unroll
      for (int mi = 0; mi < 2; ++mi)
        af[mi] = *(const bf16x8*)&As[((kk * 4 + g) * 64 + wr * 32 + mi * 16 + r16) * 8];
#pragma unroll
      for (int ni = 0; ni < 4; ++ni) {
        int n = wc * 64 + ni * 16 + r16;
        unsigned ba = (unsigned)(((kk * 4 + g) * 128 + n) * 16) ^ ((((unsigned)n >> 3) & 7u) << 4);
        bfr[ni] = *(const bf16x8*)((char*)&Bs[0] + ba);
      }
#pragma unroll
      for (int mi = 0; mi < 2; ++mi)
#pragma unroll
        for (int ni = 0; ni < 4; ++ni)
          acc[mi][ni] = __builtin_amdgcn_mfma_f32_16x16x32_bf16(
              af[mi], bfr[ni], acc[mi][ni], 0, 0, 0);
    }
    __syncthreads();
  }
  float sw[2][4];
#pragma unroll
  for (int mi = 0; mi < 2; ++mi)
#pragma unroll
    for (int r = 0; r < 4; ++r)
      sw[mi][r] = slot_weight[slot0 + wr * 32 + mi * 16 + g * 4 + r];
#pragma unroll
  for (int mi = 0; mi < 2; ++mi)
#pragma unroll
    for (int ni = 0; ni < 4; ++ni)
#pragma unroll
      for (int r = 0; r < 4; ++r) {
        int m = wr * 32 + mi * 16 + g * 4 + r;
        int n = nb + wc * 64 + ni * 16 + r16;
        slot_out[(size_t)(slot0 + m) * kH + n] = sw[mi][r] * acc[mi][ni][r];
      }
}

__global__ __launch_bounds__(256) void fb_combine(
    const float* __restrict__ slot_out, const int* __restrict__ token_slots,
    float* __restrict__ out) {
  int idx = blockIdx.x * 256 + threadIdx.x;
  int t = idx >> 8;
  int c = (idx & 255) * 4;
  int s0 = token_slots[t * 2];
  int s1 = token_slots[t * 2 + 1];
  float4 a = *(const float4*)(slot_out + (size_t)s0 * kH + c);
  float4 b = *(const float4*)(slot_out + (size_t)s1 * kH + c);
  float4 o;
  o.x = a.x + b.x; o.y = a.y + b.y; o.z = a.z + b.z; o.w = a.w + b.w;
  *(float4*)(out + (size_t)t * kH + c) = o;
}

// ============================== launcher ====================================
extern "C" void kernel_launch(void* const* d_in, const int* in_sizes, int n_in,
                              void* d_out, int out_size, void* d_ws, size_t ws_size,
                              hipStream_t stream) {
  (void)in_sizes; (void)n_in; (void)out_size;
  const float* hs  = (const float*)d_in[0];
  const float* gw  = (const float*)d_in[1];
  const float* w1s = (const float*)d_in[2];
  const float* w2s = (const float*)d_in[3];
  const float* w3s = (const float*)d_in[4];
  float* out = (float*)d_out;
  char* ws = (char*)d_ws;

  // shared control region (slot arrays padded to kSlotPad)
  int*   cnt         = (int*)(ws + 0);
  int*   cursor      = (int*)(ws + 64);
  int*   off         = (int*)(ws + 128);
  int*   tok_e       = (int*)(ws + 256);      // 16384 B
  float* tok_w       = (float*)(ws + 16640);  // 16384 B
  int*   token_slots = (int*)(ws + 33024);    // 16384 B
  int*   slot_token  = (int*)(ws + 49408);    // kSlotPad*4 = 18944 B
  float* slot_weight = (float*)(ws + 68352);  // 18944 B -> ends 87296

  // prep-path layout (regions overlaid across phases) — same NEED as r2
  constexpr size_t OFF_HSB   = 131072;
  constexpr size_t OFF_W1T   = OFF_HSB + (size_t)kT * kH * 2;         // 4,325,376
  constexpr size_t SZ_WT     = (size_t)kNE * kH * kI * 2;             // 67,108,864
  constexpr size_t OFF_W3T   = OFF_W1T + SZ_WT;                       // 71,434,240
  constexpr size_t OFF_INTER = OFF_W3T + SZ_WT;                       // 138,543,104
  constexpr size_t SZ_INTER  = (size_t)kMaxSlots * kI * 2;            // 37,748,736
  constexpr size_t NEED      = OFF_INTER + SZ_INTER;                  // 176,291,840

  hipMemsetAsync(ws, 0, 256, stream);
  router_kernel<<<kT / 4, 256, 0, stream>>>(hs, gw, cnt, tok_e, tok_w);
  offsets_kernel<<<1, 256, 0, stream>>>(cnt, off, slot_token, slot_weight);
  assign_kernel<<<kT / 256, 256, 0, stream>>>(tok_e, tok_w, off, cursor,
                                              slot_token, slot_weight, token_slots);

  if (ws_size >= NEED) {
    short* hsb      = (short*)(ws + OFF_HSB);
    short* w1t      = (short*)(ws + OFF_W1T);
    short* w3t      = (short*)(ws + OFF_W3T);
    short* w2t      = (short*)(ws + OFF_W1T);   // reuse after g1
    short* inter    = (short*)(ws + OFF_INTER);
    float* slot_out = (float*)(ws + OFF_W3T);   // reuse after g1

    conv_hs_kernel<<<(kT * kH / 8) / 256, 256, 0, stream>>>(hs, hsb);
    tconv13_kernel<<<dim3(kI / 64, kH / 64, 2 * kNE), 256, 0, stream>>>(
        w1s, w3s, w1t, w3t);
    g1_kernel<<<dim3(kI / 128, kT / 128, kNE), 512, 0, stream>>>(
        hsb, w1t, w3t, cnt, off, slot_token, inter);
    tconv_kernel<<<dim3(kH / 64, kI / 64, kNE), 256, 0, stream>>>(w2s, w2t, kI, kH);
    g2_kernel<<<dim3(kH / 128, kT / 128, kNE * 2), 512, 0, stream>>>(
        inter, w2t, cnt, off, slot_weight, slot_out);
    combine4_kernel<<<(kT * kH / 4) / 256, 256, 0, stream>>>(slot_out, token_slots, out);
  } else {
    // fallback: r1 layout (shifted clear of the padded control region)
    float* slot_out = (float*)(ws + 131072);
    short* inter    = (short*)(ws + 131072 + 18874368);
    fb_mlp1<<<dim3(kI / 128, kT / 64, kNE), 256, 0, stream>>>(
        hs, w1s, w3s, cnt, off, slot_token, inter);
    fb_mlp2<<<dim3(kH / 128, kT / 64, kNE), 256, 0, stream>>>(
        inter, w2s, cnt, off, slot_weight, slot_out);
    fb_combine<<<(kT * kH / 4) / 256, 256, 0, stream>>>(slot_out, token_slots, out);
  }
}

// Round 4
// 384.688 us; speedup vs baseline: 1.2197x; 1.2197x over previous
//
#include <hip/hip_runtime.h>
#include <hip/hip_bf16.h>
#include <math.h>

// MoE: 8 experts, top-2, H=1024, I=4096, T=2048. f32 in/out, bf16 MFMA inside.
// Round 4: 32x32x16 MFMA (2x LDS efficiency), packed-interleaved w13 so the
// dual GEMM + silu*mul is one GEMM with in-register epilogue, 128x128 blocks,
// 4 waves, single-buffer LDS, high occupancy (~3 blocks/CU).
constexpr int kNE = 8;
constexpr int kH  = 1024;
constexpr int kI  = 4096;
constexpr int kT  = 2048;
constexpr int kMaxSlots = kT * 2 + kNE * 64;   // 4608 (segments padded to 64)
constexpr int kSlotPad  = kMaxSlots + 128;

typedef short bf16x8 __attribute__((ext_vector_type(8)));
typedef float f32x4  __attribute__((ext_vector_type(4)));
typedef float f32x16 __attribute__((ext_vector_type(16)));

__device__ __forceinline__ short f2bf(float f) {
  union { float f; unsigned u; } v; v.f = f;
  unsigned r = v.u + 0x7fffu + ((v.u >> 16) & 1u);   // RNE
  return (short)(r >> 16);
}

__device__ __forceinline__ void gload16(const void* g, void* lds) {
  __builtin_amdgcn_global_load_lds(
      (const __attribute__((address_space(1))) void*)g,
      (__attribute__((address_space(3))) void*)lds, 16, 0, 0);
}

// ---------------- router: logits, top-2, renormalized weights ----------------
__global__ __launch_bounds__(256) void router_kernel(
    const float* __restrict__ hs, const float* __restrict__ gw,
    int* __restrict__ cnt, int* __restrict__ tok_e, float* __restrict__ tok_w) {
  const int lane = threadIdx.x & 63;
  const int wid  = threadIdx.x >> 6;
  const int t = blockIdx.x * 4 + wid;
  const float* hrow = hs + (size_t)t * kH;
  float acc[kNE];
#pragma unroll
  for (int e = 0; e < kNE; ++e) acc[e] = 0.f;
  for (int i = lane; i < kH; i += 64) {
    float x = hrow[i];
    float4 g0 = *(const float4*)(gw + (size_t)i * kNE);
    float4 g1 = *(const float4*)(gw + (size_t)i * kNE + 4);
    acc[0] += x * g0.x; acc[1] += x * g0.y; acc[2] += x * g0.z; acc[3] += x * g0.w;
    acc[4] += x * g1.x; acc[5] += x * g1.y; acc[6] += x * g1.z; acc[7] += x * g1.w;
  }
#pragma unroll
  for (int o = 32; o; o >>= 1)
#pragma unroll
    for (int e = 0; e < kNE; ++e) acc[e] += __shfl_xor(acc[e], o);
  if (lane == 0) {
    int e0 = 0;
#pragma unroll
    for (int e = 1; e < kNE; ++e) if (acc[e] > acc[e0]) e0 = e;
    int e1 = (e0 == 0) ? 1 : 0;
#pragma unroll
    for (int e = 0; e < kNE; ++e) if (e != e0 && acc[e] > acc[e1]) e1 = e;
    float d  = acc[e1] - acc[e0];                 // <= 0
    float w0 = 1.f / (1.f + expf(d));
    float w1 = 1.f / (1.f + expf(-d));
    atomicAdd(&cnt[e0], 1);
    atomicAdd(&cnt[e1], 1);
    tok_e[t * 2] = e0; tok_e[t * 2 + 1] = e1;
    tok_w[t * 2] = w0; tok_w[t * 2 + 1] = w1;
  }
}

// ------------- segment offsets (padded to 64) + slot-array init --------------
__global__ __launch_bounds__(256) void offsets_kernel(
    const int* __restrict__ cnt, int* __restrict__ off,
    int* __restrict__ slot_token, float* __restrict__ slot_weight) {
  if (threadIdx.x == 0) {
    int o = 0;
#pragma unroll
    for (int e = 0; e < kNE; ++e) { off[e] = o; o += (cnt[e] + 63) & ~63; }
    off[kNE] = o;
  }
  for (int i = threadIdx.x; i < kSlotPad; i += 256) {
    slot_token[i]  = -1;
    slot_weight[i] = 0.f;
  }
}

// ---------------- scatter tokens into expert slot segments ------------------
__global__ __launch_bounds__(256) void assign_kernel(
    const int* __restrict__ tok_e, const float* __restrict__ tok_w,
    const int* __restrict__ off, int* __restrict__ cursor,
    int* __restrict__ slot_token, float* __restrict__ slot_weight,
    int* __restrict__ token_slots) {
  const int t = blockIdx.x * 256 + threadIdx.x;
  if (t >= kT) return;
#pragma unroll
  for (int k = 0; k < 2; ++k) {
    int e = tok_e[t * 2 + k];
    int pos = off[e] + atomicAdd(&cursor[e], 1);
    slot_token[pos]  = t;
    slot_weight[pos] = tok_w[t * 2 + k];
    token_slots[t * 2 + k] = pos;
  }
}

// ------------------- hs f32 -> bf16 (row-major, unchanged) ------------------
__global__ __launch_bounds__(256) void conv_hs_kernel(
    const float* __restrict__ hs, short* __restrict__ hsb) {
  const int idx = blockIdx.x * 256 + threadIdx.x;     // 8 elems each
  const float* p = hs + (size_t)idx * 8;
  float4 a = *(const float4*)p;
  float4 b = *(const float4*)(p + 4);
  bf16x8 w;
  w[0] = f2bf(a.x); w[1] = f2bf(a.y); w[2] = f2bf(a.z); w[3] = f2bf(a.w);
  w[4] = f2bf(b.x); w[5] = f2bf(b.y); w[6] = f2bf(b.z); w[7] = f2bf(b.w);
  *(bf16x8*)(hsb + (size_t)idx * 8) = w;
}

// ---- w1/w3 transpose+convert+PACK: f32 [E][K][4096] -> bf16 [E][8192][K] ---
// Packed col c: b=c>>6, s=(c>>5)&1, c32=c&31 -> (s?w3:w1) col b*32+c32.
// So a wave's 64-packed-col span = {w1 cols b*32..+31 | w3 cols b*32..+31}.
__global__ __launch_bounds__(256) void tconv13p_kernel(
    const float* __restrict__ w1s, const float* __restrict__ w3s,
    short* __restrict__ w13t) {
  __shared__ float tile[64][65];
  const int z = blockIdx.z;
  const int e = z & 7, sel = z >> 3;
  const float* src = (sel ? w3s : w1s) + (size_t)e * kH * kI;
  const int n0 = blockIdx.x * 64, k0 = blockIdx.y * 64;
  const int tid = threadIdx.x;
  const int tn = (tid & 15) * 4, tk = tid >> 4;
#pragma unroll
  for (int i = 0; i < 4; ++i) {
    float4 v = *(const float4*)(src + (size_t)(k0 + tk + i * 16) * kI + n0 + tn);
    tile[tk + i * 16][tn] = v.x; tile[tk + i * 16][tn + 1] = v.y;
    tile[tk + i * 16][tn + 2] = v.z; tile[tk + i * 16][tn + 3] = v.w;
  }
  __syncthreads();
  const int kc = tid & 7;
#pragma unroll
  for (int i = 0; i < 2; ++i) {
    const int n = (tid >> 3) + i * 32;
    bf16x8 w;
#pragma unroll
    for (int j = 0; j < 8; ++j) w[j] = f2bf(tile[kc * 8 + j][n]);
    const int sn = n0 + n;
    const int pc = (sn >> 5) * 64 + sel * 32 + (sn & 31);
    *(bf16x8*)(w13t + ((size_t)e * 8192 + pc) * kH + k0 + kc * 8) = w;
  }
}

// ------- generic transpose+convert: f32 [E][K][N] -> bf16 [E][N][K] ---------
__global__ __launch_bounds__(256) void tconv_kernel(
    const float* __restrict__ src0, short* __restrict__ dst0, int K, int N) {
  __shared__ float tile[64][65];
  const int e = blockIdx.z;
  const float* src = src0 + (size_t)e * K * N;
  short* dst = dst0 + (size_t)e * K * N;
  const int n0 = blockIdx.x * 64, k0 = blockIdx.y * 64;
  const int tid = threadIdx.x;
  const int tn = (tid & 15) * 4, tk = tid >> 4;
#pragma unroll
  for (int i = 0; i < 4; ++i) {
    float4 v = *(const float4*)(src + (size_t)(k0 + tk + i * 16) * N + n0 + tn);
    tile[tk + i * 16][tn] = v.x; tile[tk + i * 16][tn + 1] = v.y;
    tile[tk + i * 16][tn + 2] = v.z; tile[tk + i * 16][tn + 3] = v.w;
  }
  __syncthreads();
  const int kc = tid & 7;
#pragma unroll
  for (int i = 0; i < 2; ++i) {
    int n = (tid >> 3) + i * 32;
    bf16x8 w;
#pragma unroll
    for (int j = 0; j < 8; ++j) w[j] = f2bf(tile[kc * 8 + j][n]);
    *(bf16x8*)(dst + (size_t)(n0 + n) * K + k0 + kc * 8) = w;
  }
}

// --------- GEMM1: inter = silu(x@w1)*(x@w3) via packed w13, 32x32 MFMA ------
// Block 128m x 128pc, 4 waves (2x2), wave 64x64, BK=64, single-buffer LDS.
// LDS layout [row][slot], slot = kchunk ^ (row&7) (16B granules, 128B rows).
__global__ __launch_bounds__(256, 3) void g1_kernel(
    const short* __restrict__ hsb, const short* __restrict__ w13t,
    const int* __restrict__ cnt, const int* __restrict__ off,
    const int* __restrict__ slot_token, short* __restrict__ inter) {
  const int e = blockIdx.z;
  const int count = cnt[e];
  const int rb = blockIdx.y;
  if (rb * 128 >= count) return;
  const int slot0 = off[e] + rb * 128;
  const int mlim = ((count + 63) & ~63) - rb * 128;
  const int nb = blockIdx.x;                       // 0..63 (128 packed cols)

  __shared__ __align__(16) short As[128 * 64];     // 16KB
  __shared__ __align__(16) short Bs[128 * 64];     // 16KB

  const int tid = threadIdx.x;
  const int l = tid & 63, w = tid >> 6;
  const int wr = w >> 1, wc = w & 1;

  // staging: instr q=w*4+i covers rows q*8..q*8+7; lane: row q*8+(l>>3),
  // LDS slot l&7; source chunk = (l&7) ^ ((l>>3)&7)  (inverse swizzle).
  const int srow = l >> 3;
  const int sch  = (l & 7) ^ srow;
  const short* aptr[4];
  const short* bptr[4];
  unsigned sdst[4];
#pragma unroll
  for (int i = 0; i < 4; ++i) {
    const int q = w * 4 + i;
    const int row = q * 8 + srow;
    int tok = slot_token[slot0 + row]; if (tok < 0) tok = 0;
    aptr[i] = hsb + (size_t)tok * kH + sch * 8;
    bptr[i] = w13t + ((size_t)e * 8192 + nb * 128 + row) * kH + sch * 8;
    sdst[i] = (unsigned)(q * 1024 + l * 16);
  }

  f32x16 acc[2][2];
#pragma unroll
  for (int mi = 0; mi < 2; ++mi)
#pragma unroll
    for (int ni = 0; ni < 2; ++ni)
#pragma unroll
      for (int r = 0; r < 16; ++r) acc[mi][ni][r] = 0.f;

  const int l31 = l & 31, lhi = l >> 5;

  for (int t = 0; t < kH / 64; ++t) {
    const int k0 = t * 64;
#pragma unroll
    for (int i = 0; i < 4; ++i) {
      gload16(aptr[i] + k0, (char*)As + sdst[i]);
      gload16(bptr[i] + k0, (char*)Bs + sdst[i]);
    }
    __syncthreads();
#pragma unroll
    for (int kk = 0; kk < 4; ++kk) {
      const int chk = kk * 2 + lhi;
      bf16x8 af[2], bf[2];
#pragma unroll
      for (int mi = 0; mi < 2; ++mi) {
        const int m = wr * 64 + mi * 32 + l31;
        af[mi] = *(const bf16x8*)((const char*)As + m * 128 + ((chk ^ (m & 7)) * 16));
      }
#pragma unroll
      for (int ni = 0; ni < 2; ++ni) {
        const int n = wc * 64 + ni * 32 + l31;
        bf[ni] = *(const bf16x8*)((const char*)Bs + n * 128 + ((chk ^ (n & 7)) * 16));
      }
#pragma unroll
      for (int mi = 0; mi < 2; ++mi)
#pragma unroll
        for (int ni = 0; ni < 2; ++ni)
          acc[mi][ni] = __builtin_amdgcn_mfma_f32_32x32x16_bf16(
              af[mi], bf[ni], acc[mi][ni], 0, 0, 0);
    }
    __syncthreads();
  }

  // epilogue: acc[mi][0]=h1, acc[mi][1]=h3 for real col (nb*2+wc)*32 + l31
  const int colb = (nb * 2 + wc) * 32 + l31;
#pragma unroll
  for (int mi = 0; mi < 2; ++mi)
#pragma unroll
    for (int r = 0; r < 16; ++r) {
      const int m = wr * 64 + mi * 32 + (r & 3) + 8 * (r >> 2) + 4 * lhi;
      if (m < mlim) {
        float h1 = acc[mi][0][r];
        float h3 = acc[mi][1][r];
        float y = h1 / (1.f + expf(-h1)) * h3;
        inter[(size_t)(slot0 + m) * kI + colb] = f2bf(y);
      }
    }
}

// --------- GEMM2: slot_out = w_slot * (inter @ w2), split-K=2, 32x32 --------
__global__ __launch_bounds__(256, 3) void g2_kernel(
    const short* __restrict__ inter, const short* __restrict__ w2t,
    const int* __restrict__ cnt, const int* __restrict__ off,
    const float* __restrict__ slot_weight, float* __restrict__ slot_out) {
  const int zz = blockIdx.z;
  const int e = zz & 7, half = zz >> 3;
  const int count = cnt[e];
  const int rb = blockIdx.y;
  if (rb * 128 >= count) return;
  const int slot0 = off[e] + rb * 128;
  const int mlim = ((count + 63) & ~63) - rb * 128;
  const int nb = blockIdx.x;                       // 0..7 (128 cols)
  const int kbase = half * (kI / 2);

  __shared__ __align__(16) short As[128 * 64];
  __shared__ __align__(16) short Bs[128 * 64];

  const int tid = threadIdx.x;
  const int l = tid & 63, w = tid >> 6;
  const int wr = w >> 1, wc = w & 1;

  const int srow = l >> 3;
  const int sch  = (l & 7) ^ srow;
  const short* aptr[4];
  const short* bptr[4];
  unsigned sdst[4];
#pragma unroll
  for (int i = 0; i < 4; ++i) {
    const int q = w * 4 + i;
    const int row = q * 8 + srow;
    int sr = slot0 + row; if (sr >= kMaxSlots) sr = kMaxSlots - 1;
    aptr[i] = inter + (size_t)sr * kI + kbase + sch * 8;
    bptr[i] = w2t + ((size_t)e * kH + nb * 128 + row) * kI + kbase + sch * 8;
    sdst[i] = (unsigned)(q * 1024 + l * 16);
  }

  f32x16 acc[2][2];
#pragma unroll
  for (int mi = 0; mi < 2; ++mi)
#pragma unroll
    for (int ni = 0; ni < 2; ++ni)
#pragma unroll
      for (int r = 0; r < 16; ++r) acc[mi][ni][r] = 0.f;

  const int l31 = l & 31, lhi = l >> 5;

  for (int t = 0; t < (kI / 2) / 64; ++t) {
    const int k0 = t * 64;
#pragma unroll
    for (int i = 0; i < 4; ++i) {
      gload16(aptr[i] + k0, (char*)As + sdst[i]);
      gload16(bptr[i] + k0, (char*)Bs + sdst[i]);
    }
    __syncthreads();
#pragma unroll
    for (int kk = 0; kk < 4; ++kk) {
      const int chk = kk * 2 + lhi;
      bf16x8 af[2], bf[2];
#pragma unroll
      for (int mi = 0; mi < 2; ++mi) {
        const int m = wr * 64 + mi * 32 + l31;
        af[mi] = *(const bf16x8*)((const char*)As + m * 128 + ((chk ^ (m & 7)) * 16));
      }
#pragma unroll
      for (int ni = 0; ni < 2; ++ni) {
        const int n = wc * 64 + ni * 32 + l31;
        bf[ni] = *(const bf16x8*)((const char*)Bs + n * 128 + ((chk ^ (n & 7)) * 16));
      }
#pragma unroll
      for (int mi = 0; mi < 2; ++mi)
#pragma unroll
        for (int ni = 0; ni < 2; ++ni)
          acc[mi][ni] = __builtin_amdgcn_mfma_f32_32x32x16_bf16(
              af[mi], bf[ni], acc[mi][ni], 0, 0, 0);
    }
    __syncthreads();
  }

#pragma unroll
  for (int mi = 0; mi < 2; ++mi)
#pragma unroll
    for (int r = 0; r < 16; ++r) {
      const int m = wr * 64 + mi * 32 + (r & 3) + 8 * (r >> 2) + 4 * lhi;
      if (m < mlim) {
        const float sw = slot_weight[slot0 + m];
        const size_t orow = ((size_t)half * kMaxSlots + slot0 + m) * kH;
#pragma unroll
        for (int ni = 0; ni < 2; ++ni)
          slot_out[orow + nb * 128 + wc * 64 + ni * 32 + l31] =
              sw * acc[mi][ni][r];
      }
    }
}

// ------- combine: out[t] = sum over 2 slots x 2 K-halves of slot_out --------
__global__ __launch_bounds__(256) void combine4_kernel(
    const float* __restrict__ slot_out, const int* __restrict__ token_slots,
    float* __restrict__ out) {
  int idx = blockIdx.x * 256 + threadIdx.x;
  int t = idx >> 8;
  int c = (idx & 255) * 4;
  int s0 = token_slots[t * 2];
  int s1 = token_slots[t * 2 + 1];
  const size_t HS = (size_t)kMaxSlots * kH;
  float4 a = *(const float4*)(slot_out + (size_t)s0 * kH + c);
  float4 b = *(const float4*)(slot_out + (size_t)s1 * kH + c);
  float4 a2 = *(const float4*)(slot_out + HS + (size_t)s0 * kH + c);
  float4 b2 = *(const float4*)(slot_out + HS + (size_t)s1 * kH + c);
  float4 o;
  o.x = a.x + b.x + a2.x + b2.x; o.y = a.y + b.y + a2.y + b2.y;
  o.z = a.z + b.z + a2.z + b2.z; o.w = a.w + b.w + a2.w + b2.w;
  *(float4*)(out + (size_t)t * kH + c) = o;
}

// ===================== fallback path (r1, in-loop convert) ==================
__global__ __launch_bounds__(256) void fb_mlp1(
    const float* __restrict__ hs,
    const float* __restrict__ w1s, const float* __restrict__ w3s,
    const int* __restrict__ cnt, const int* __restrict__ off,
    const int* __restrict__ slot_token, short* __restrict__ inter) {
  const int e = blockIdx.z;
  const int count = cnt[e];
  const int rb = blockIdx.y;
  if (rb * 64 >= count) return;
  const int slot0 = off[e] + rb * 64;
  const int nb = blockIdx.x * 128;
  __shared__ __align__(16) short As[4 * 64 * 8];
  __shared__ __align__(16) short Bs[2][4 * 128 * 8];
  const int tid  = threadIdx.x;
  const int lane = tid & 63;
  const int wid  = tid >> 6;
  const int wr = wid >> 1, wc = wid & 1;
  const int am = tid & 63, akb = tid >> 6;
  int tok = slot_token[slot0 + am];
  if (tok < 0) tok = 0;
  const float* arow = hs + (size_t)tok * kH + akb * 8;
  const int which = tid >> 7;
  const int bn0 = (tid & 31) * 4;
  const int bkb = (tid >> 5) & 3;
  const float* wbase = (which ? w3s : w1s) +
      (size_t)e * kH * kI + (size_t)(bkb * 8) * kI + nb + bn0;
  char* bdstp = (char*)&Bs[which][0];
  f32x4 acc[2][2][4];
#pragma unroll
  for (int s = 0; s < 2; ++s)
#pragma unroll
    for (int mi = 0; mi < 2; ++mi)
#pragma unroll
      for (int ni = 0; ni < 4; ++ni)
#pragma unroll
        for (int r = 0; r < 4; ++r) acc[s][mi][ni][r] = 0.f;
  const int g = lane >> 4, r16 = lane & 15;
  for (int k0 = 0; k0 < kH; k0 += 32) {
    float4 a0 = *(const float4*)(arow + k0);
    float4 a1 = *(const float4*)(arow + k0 + 4);
    bf16x8 av;
    av[0] = f2bf(a0.x); av[1] = f2bf(a0.y); av[2] = f2bf(a0.z); av[3] = f2bf(a0.w);
    av[4] = f2bf(a1.x); av[5] = f2bf(a1.y); av[6] = f2bf(a1.z); av[7] = f2bf(a1.w);
    *(bf16x8*)&As[(akb * 64 + am) * 8] = av;
    {
      const float* bp = wbase + (size_t)k0 * kI;
      float4 v[8];
#pragma unroll
      for (int j = 0; j < 8; ++j) v[j] = *(const float4*)(bp + (size_t)j * kI);
      const float* vf = (const float*)v;
#pragma unroll
      for (int i = 0; i < 4; ++i) {
        bf16x8 w;
#pragma unroll
        for (int j = 0; j < 8; ++j) w[j] = f2bf(vf[j * 4 + i]);
        int n = bn0 + i;
        unsigned ba = (unsigned)((bkb * 128 + n) * 16) ^ ((((unsigned)n >> 3) & 7u) << 4);
        *(bf16x8*)(bdstp + ba) = w;
      }
    }
    __syncthreads();
    bf16x8 af[2], bfr[2][4];
#pragma unroll
    for (int mi = 0; mi < 2; ++mi)
      af[mi] = *(const bf16x8*)&As[(g * 64 + wr * 32 + mi * 16 + r16) * 8];
#pragma unroll
    for (int s = 0; s < 2; ++s)
#pragma unroll
      for (int ni = 0; ni < 4; ++ni) {
        int n = wc * 64 + ni * 16 + r16;
        unsigned ba = (unsigned)((g * 128 + n) * 16) ^ ((((unsigned)n >> 3) & 7u) << 4);
        bfr[s][ni] = *(const bf16x8*)((char*)&Bs[s][0] + ba);
      }
#pragma unroll
    for (int s = 0; s < 2; ++s)
#pragma unroll
      for (int mi = 0; mi < 2; ++mi)
#pragma unroll
        for (int ni = 0; ni < 4; ++ni)
          acc[s][mi][ni] = __builtin_amdgcn_mfma_f32_16x16x32_bf16(
              af[mi], bfr[s][ni], acc[s][mi][ni], 0, 0, 0);
    __syncthreads();
  }
#pragma unroll
  for (int mi = 0; mi < 2; ++mi)
#pragma unroll
    for (int ni = 0; ni < 4; ++ni)
#pragma unroll
      for (int r = 0; r < 4; ++r) {
        float h1 = acc[0][mi][ni][r];
        float h3 = acc[1][mi][ni][r];
        float y = h1 / (1.f + expf(-h1)) * h3;
        int m = wr * 32 + mi * 16 + g * 4 + r;
        int n = nb + wc * 64 + ni * 16 + r16;
        inter[(size_t)(slot0 + m) * kI + n] = f2bf(y);
      }
}

__global__ __launch_bounds__(256) void fb_mlp2(
    const short* __restrict__ inter, const float* __restrict__ w2s,
    const int* __restrict__ cnt, const int* __restrict__ off,
    const float* __restrict__ slot_weight, float* __restrict__ slot_out) {
  const int e = blockIdx.z;
  const int count = cnt[e];
  const int rb = blockIdx.y;
  if (rb * 64 >= count) return;
  const int slot0 = off[e] + rb * 64;
  const int nb = blockIdx.x * 128;
  __shared__ __align__(16) short As[8 * 64 * 8];
  __shared__ __align__(16) short Bs[8 * 128 * 8];
  const int tid  = threadIdx.x;
  const int lane = tid & 63;
  const int wid  = tid >> 6;
  const int wr = wid >> 1, wc = wid & 1;
  const int am = tid & 63, akb = tid >> 6;
  const short* arow = inter + (size_t)(slot0 + am) * kI;
  const int bn0 = (tid & 31) * 4;
  const int bkb = tid >> 5;
  const float* wbase = w2s + (size_t)e * kI * kH + (size_t)(bkb * 8) * kH + nb + bn0;
  f32x4 acc[2][4];
#pragma unroll
  for (int mi = 0; mi < 2; ++mi)
#pragma unroll
    for (int ni = 0; ni < 4; ++ni)
#pragma unroll
      for (int r = 0; r < 4; ++r) acc[mi][ni][r] = 0.f;
  const int g = lane >> 4, r16 = lane & 15;
  for (int k0 = 0; k0 < kI; k0 += 64) {
    bf16x8 x0 = *(const bf16x8*)(arow + k0 + akb * 8);
    bf16x8 x1 = *(const bf16x8*)(arow + k0 + (akb + 4) * 8);
    *(bf16x8*)&As[(akb * 64 + am) * 8] = x0;
    *(bf16x8*)&As[((akb + 4) * 64 + am) * 8] = x1;
    {
      const float* bp = wbase + (size_t)k0 * kH;
      float4 v[8];
#pragma unroll
      for (int j = 0; j < 8; ++j) v[j] = *(const float4*)(bp + (size_t)j * kH);
      const float* vf = (const float*)v;
#pragma unroll
      for (int i = 0; i < 4; ++i) {
        bf16x8 w;
#pragma unroll
        for (int j = 0; j < 8; ++j) w[j] = f2bf(vf[j * 4 + i]);
        int n = bn0 + i;
        unsigned ba = (unsigned)((bkb * 128 + n) * 16) ^ ((((unsigned)n >> 3) & 7u) << 4);
        *(bf16x8*)((char*)&Bs[0] + ba) = w;
      }
    }
    __syncthreads();
#pragma unroll
    for (int kk = 0; kk < 2; ++kk) {
      bf16x8 af[2], bfr[4];
#pragma unroll
      for (int mi = 0; mi < 2; ++mi)
        af[mi] = *(const bf16x8*)&As[((kk * 4 + g) * 64 + wr * 32 + mi * 16 + r16) * 8];
#pragma unroll
      for (int ni = 0; ni < 4; ++ni) {
        int n = wc * 64 + ni * 16 + r16;
        unsigned ba = (unsigned)(((kk * 4 + g) * 128 + n) * 16) ^ ((((unsigned)n >> 3) & 7u) << 4);
        bfr[ni] = *(const bf16x8*)((char*)&Bs[0] + ba);
      }
#pragma unroll
      for (int mi = 0; mi < 2; ++mi)
#pragma unroll
        for (int ni = 0; ni < 4; ++ni)
          acc[mi][ni] = __builtin_amdgcn_mfma_f32_16x16x32_bf16(
              af[mi], bfr[ni], acc[mi][ni], 0, 0, 0);
    }
    __syncthreads();
  }
  float sw[2][4];
#pragma unroll
  for (int mi = 0; mi < 2; ++mi)
#pragma unroll
    for (int r = 0; r < 4; ++r)
      sw[mi][r] = slot_weight[slot0 + wr * 32 + mi * 16 + g * 4 + r];
#pragma unroll
  for (int mi = 0; mi < 2; ++mi)
#pragma unroll
    for (int ni = 0; ni < 4; ++ni)
#pragma unroll
      for (int r = 0; r < 4; ++r) {
        int m = wr * 32 + mi * 16 + g * 4 + r;
        int n = nb + wc * 64 + ni * 16 + r16;
        slot_out[(size_t)(slot0 + m) * kH + n] = sw[mi][r] * acc[mi][ni][r];
      }
}

__global__ __launch_bounds__(256) void fb_combine(
    const float* __restrict__ slot_out, const int* __restrict__ token_slots,
    float* __restrict__ out) {
  int idx = blockIdx.x * 256 + threadIdx.x;
  int t = idx >> 8;
  int c = (idx & 255) * 4;
  int s0 = token_slots[t * 2];
  int s1 = token_slots[t * 2 + 1];
  float4 a = *(const float4*)(slot_out + (size_t)s0 * kH + c);
  float4 b = *(const float4*)(slot_out + (size_t)s1 * kH + c);
  float4 o;
  o.x = a.x + b.x; o.y = a.y + b.y; o.z = a.z + b.z; o.w = a.w + b.w;
  *(float4*)(out + (size_t)t * kH + c) = o;
}

// ============================== launcher ====================================
extern "C" void kernel_launch(void* const* d_in, const int* in_sizes, int n_in,
                              void* d_out, int out_size, void* d_ws, size_t ws_size,
                              hipStream_t stream) {
  (void)in_sizes; (void)n_in; (void)out_size;
  const float* hs  = (const float*)d_in[0];
  const float* gw  = (const float*)d_in[1];
  const float* w1s = (const float*)d_in[2];
  const float* w2s = (const float*)d_in[3];
  const float* w3s = (const float*)d_in[4];
  float* out = (float*)d_out;
  char* ws = (char*)d_ws;

  // shared control region
  int*   cnt         = (int*)(ws + 0);
  int*   cursor      = (int*)(ws + 64);
  int*   off         = (int*)(ws + 128);
  int*   tok_e       = (int*)(ws + 256);
  float* tok_w       = (float*)(ws + 16640);
  int*   token_slots = (int*)(ws + 33024);
  int*   slot_token  = (int*)(ws + 49408);
  float* slot_weight = (float*)(ws + 68352);

  // prep-path layout (overlaid; NEED identical to r2/r3 = 176,291,840 B)
  constexpr size_t OFF_HSB     = 131072;
  constexpr size_t OFF_W13T    = OFF_HSB + (size_t)kT * kH * 2;     // 4,325,376
  constexpr size_t SZ_W13T     = (size_t)kNE * 8192 * kH * 2;       // 134,217,728
  constexpr size_t OFF_INTER   = OFF_W13T + SZ_W13T;                // 138,543,104
  constexpr size_t SZ_INTER    = (size_t)kMaxSlots * kI * 2;        // 37,748,736
  constexpr size_t NEED        = OFF_INTER + SZ_INTER;              // 176,291,840
  constexpr size_t OFF_W2T     = OFF_W13T;                          // overlay after g1
  constexpr size_t OFF_SLOTOUT = OFF_W13T + (size_t)kNE * kH * kI * 2; // 71,434,240

  hipMemsetAsync(ws, 0, 256, stream);
  router_kernel<<<kT / 4, 256, 0, stream>>>(hs, gw, cnt, tok_e, tok_w);
  offsets_kernel<<<1, 256, 0, stream>>>(cnt, off, slot_token, slot_weight);
  assign_kernel<<<kT / 256, 256, 0, stream>>>(tok_e, tok_w, off, cursor,
                                              slot_token, slot_weight, token_slots);

  if (ws_size >= NEED) {
    short* hsb      = (short*)(ws + OFF_HSB);
    short* w13t     = (short*)(ws + OFF_W13T);
    short* w2t      = (short*)(ws + OFF_W2T);
    short* inter    = (short*)(ws + OFF_INTER);
    float* slot_out = (float*)(ws + OFF_SLOTOUT);

    conv_hs_kernel<<<(kT * kH / 8) / 256, 256, 0, stream>>>(hs, hsb);
    tconv13p_kernel<<<dim3(kI / 64, kH / 64, 2 * kNE), 256, 0, stream>>>(
        w1s, w3s, w13t);
    g1_kernel<<<dim3(8192 / 128, kT / 128, kNE), 256, 0, stream>>>(
        hsb, w13t, cnt, off, slot_token, inter);
    tconv_kernel<<<dim3(kH / 64, kI / 64, kNE), 256, 0, stream>>>(w2s, w2t, kI, kH);
    g2_kernel<<<dim3(kH / 128, kT / 128, kNE * 2), 256, 0, stream>>>(
        inter, w2t, cnt, off, slot_weight, slot_out);
    combine4_kernel<<<(kT * kH / 4) / 256, 256, 0, stream>>>(slot_out, token_slots, out);
  } else {
    // fallback: r1 layout
    float* slot_out = (float*)(ws + 131072);
    short* inter    = (short*)(ws + 131072 + 18874368);
    fb_mlp1<<<dim3(kI / 128, kT / 64, kNE), 256, 0, stream>>>(
        hs, w1s, w3s, cnt, off, slot_token, inter);
    fb_mlp2<<<dim3(kH / 128, kT / 64, kNE), 256, 0, stream>>>(
        inter, w2s, cnt, off, slot_weight, slot_out);
    fb_combine<<<(kT * kH / 4) / 256, 256, 0, stream>>>(slot_out, token_slots, out);
  }
}

// Round 5
// 381.940 us; speedup vs baseline: 1.2284x; 1.0072x over previous
//
#include <hip/hip_runtime.h>
#include <hip/hip_bf16.h>
#include <math.h>

// MoE: 8 experts, top-2, H=1024, I=4096, T=2048. f32 in/out, bf16 MFMA inside.
// Round 5: 16x16x32 MFMA frags (r2-verified zero-conflict swizzle) on r4's
// 128x128/4-wave structure; write-coalesced transpose kernels (512-B segments).
constexpr int kNE = 8;
constexpr int kH  = 1024;
constexpr int kI  = 4096;
constexpr int kT  = 2048;
constexpr int kMaxSlots = kT * 2 + kNE * 64;   // 4608
constexpr int kSlotPad  = kMaxSlots + 128;

typedef short bf16x8 __attribute__((ext_vector_type(8)));
typedef float f32x4  __attribute__((ext_vector_type(4)));

__device__ __forceinline__ short f2bf(float f) {
  union { float f; unsigned u; } v; v.f = f;
  unsigned r = v.u + 0x7fffu + ((v.u >> 16) & 1u);   // RNE
  return (short)(r >> 16);
}

__device__ __forceinline__ void gload16(const void* g, void* lds) {
  __builtin_amdgcn_global_load_lds(
      (const __attribute__((address_space(1))) void*)g,
      (__attribute__((address_space(3))) void*)lds, 16, 0, 0);
}

// ---------------- router ----------------------------------------------------
__global__ __launch_bounds__(256) void router_kernel(
    const float* __restrict__ hs, const float* __restrict__ gw,
    int* __restrict__ cnt, int* __restrict__ tok_e, float* __restrict__ tok_w) {
  const int lane = threadIdx.x & 63;
  const int wid  = threadIdx.x >> 6;
  const int t = blockIdx.x * 4 + wid;
  const float* hrow = hs + (size_t)t * kH;
  float acc[kNE];
#pragma unroll
  for (int e = 0; e < kNE; ++e) acc[e] = 0.f;
  for (int i = lane; i < kH; i += 64) {
    float x = hrow[i];
    float4 g0 = *(const float4*)(gw + (size_t)i * kNE);
    float4 g1 = *(const float4*)(gw + (size_t)i * kNE + 4);
    acc[0] += x * g0.x; acc[1] += x * g0.y; acc[2] += x * g0.z; acc[3] += x * g0.w;
    acc[4] += x * g1.x; acc[5] += x * g1.y; acc[6] += x * g1.z; acc[7] += x * g1.w;
  }
#pragma unroll
  for (int o = 32; o; o >>= 1)
#pragma unroll
    for (int e = 0; e < kNE; ++e) acc[e] += __shfl_xor(acc[e], o);
  if (lane == 0) {
    int e0 = 0;
#pragma unroll
    for (int e = 1; e < kNE; ++e) if (acc[e] > acc[e0]) e0 = e;
    int e1 = (e0 == 0) ? 1 : 0;
#pragma unroll
    for (int e = 0; e < kNE; ++e) if (e != e0 && acc[e] > acc[e1]) e1 = e;
    float d  = acc[e1] - acc[e0];
    float w0 = 1.f / (1.f + expf(d));
    float w1 = 1.f / (1.f + expf(-d));
    atomicAdd(&cnt[e0], 1);
    atomicAdd(&cnt[e1], 1);
    tok_e[t * 2] = e0; tok_e[t * 2 + 1] = e1;
    tok_w[t * 2] = w0; tok_w[t * 2 + 1] = w1;
  }
}

// ------------- offsets + slot init ------------------------------------------
__global__ __launch_bounds__(256) void offsets_kernel(
    const int* __restrict__ cnt, int* __restrict__ off,
    int* __restrict__ slot_token, float* __restrict__ slot_weight) {
  if (threadIdx.x == 0) {
    int o = 0;
#pragma unroll
    for (int e = 0; e < kNE; ++e) { off[e] = o; o += (cnt[e] + 63) & ~63; }
    off[kNE] = o;
  }
  for (int i = threadIdx.x; i < kSlotPad; i += 256) {
    slot_token[i]  = -1;
    slot_weight[i] = 0.f;
  }
}

// ---------------- scatter ---------------------------------------------------
__global__ __launch_bounds__(256) void assign_kernel(
    const int* __restrict__ tok_e, const float* __restrict__ tok_w,
    const int* __restrict__ off, int* __restrict__ cursor,
    int* __restrict__ slot_token, float* __restrict__ slot_weight,
    int* __restrict__ token_slots) {
  const int t = blockIdx.x * 256 + threadIdx.x;
  if (t >= kT) return;
#pragma unroll
  for (int k = 0; k < 2; ++k) {
    int e = tok_e[t * 2 + k];
    int pos = off[e] + atomicAdd(&cursor[e], 1);
    slot_token[pos]  = t;
    slot_weight[pos] = tok_w[t * 2 + k];
    token_slots[t * 2 + k] = pos;
  }
}

// ------------------- hs f32 -> bf16 -----------------------------------------
__global__ __launch_bounds__(256) void conv_hs_kernel(
    const float* __restrict__ hs, short* __restrict__ hsb) {
  const int idx = blockIdx.x * 256 + threadIdx.x;
  const float* p = hs + (size_t)idx * 8;
  float4 a = *(const float4*)p;
  float4 b = *(const float4*)(p + 4);
  bf16x8 w;
  w[0] = f2bf(a.x); w[1] = f2bf(a.y); w[2] = f2bf(a.z); w[3] = f2bf(a.w);
  w[4] = f2bf(b.x); w[5] = f2bf(b.y); w[6] = f2bf(b.z); w[7] = f2bf(b.w);
  *(bf16x8*)(hsb + (size_t)idx * 8) = w;
}

// ----- write-coalesced transpose+convert, block = 256k x 64n ----------------
// LDS [c][k] bf16, 512-B rows, 16-B granule XOR swizzle: the 16-B chunk kc of
// col c sits at byte c*512 + ((kc ^ (c&31))*16). Phase 1: coalesced f32 row
// reads -> scalar bf16 LDS writes (2-way max). Phase 2: ds_read_b128 per
// (col, kc) -> 512-B contiguous global writes (32 lanes cover one col).
// MODE 0: w1/w3 -> packed w13t [E][8192][1024]; z = e + 8*sel.
// MODE 1: w2 -> w2t [E][1024][4096]; z = e.
template <int MODE>
__global__ __launch_bounds__(256) void tconv_v2(
    const float* __restrict__ s1, const float* __restrict__ s3,
    short* __restrict__ dst0) {
  constexpr int K = MODE ? kI : kH;
  constexpr int N = MODE ? kH : kI;
  const int z = blockIdx.z;
  const int e = z & 7, sel = z >> 3;
  const float* src = (MODE ? s1 : (sel ? s3 : s1)) + (size_t)e * kH * kI;
  const int tb = blockIdx.x;                 // 256 tiles
  const int nb = (tb & (N / 64 - 1)) * 64;
  const int kb = (tb / (N / 64)) * 256;

  __shared__ __align__(16) short lds[64 * 256];   // 32 KB

  const int tid = threadIdx.x;
  // ---- phase 1 ----
  const int rk = tid >> 4;            // 0..15
  const int rn = (tid & 15) * 4;
#pragma unroll
  for (int i = 0; i < 16; ++i) {
    const int k = rk + i * 16;        // 0..255
    float4 v = *(const float4*)(src + (size_t)(kb + k) * N + nb + rn);
    short s[4] = {f2bf(v.x), f2bf(v.y), f2bf(v.z), f2bf(v.w)};
    const int kc = k >> 3;
    const int kb2 = (k & 7) * 2;
#pragma unroll
    for (int j = 0; j < 4; ++j) {
      const int c = rn + j;
      *(short*)((char*)lds + c * 512 + ((kc ^ (c & 31)) * 16) + kb2) = s[j];
    }
  }
  __syncthreads();
  // ---- phase 2 ----
  const int l = tid & 63, w = tid >> 6;
  const int kc = l & 31;              // 16-B chunk, k = kc*8..+7
#pragma unroll
  for (int p = 0; p < 8; ++p) {
    const int c = w * 2 + (l >> 5) + p * 8;   // 0..63
    bf16x8 vv = *(const bf16x8*)((const char*)lds + c * 512 + ((kc ^ (c & 31)) * 16));
    int dc;
    if (MODE == 0) {
      const int n = nb + c;
      dc = (n >> 5) * 64 + sel * 32 + (n & 31);
      *(bf16x8*)(dst0 + ((size_t)e * 8192 + dc) * kH + kb + kc * 8) = vv;
    } else {
      dc = nb + c;
      *(bf16x8*)(dst0 + ((size_t)e * kH + dc) * kI + kb + kc * 8) = vv;
    }
  }
}

// --------- GEMM1: inter = silu(x@w1)*(x@w3), packed w13, 16x16x32 -----------
// Block 128m x 128pc, 4 waves (2x2), wave 64x64, BK=64, single-buffer LDS.
__global__ __launch_bounds__(256, 3) void g1_kernel(
    const short* __restrict__ hsb, const short* __restrict__ w13t,
    const int* __restrict__ cnt, const int* __restrict__ off,
    const int* __restrict__ slot_token, short* __restrict__ inter) {
  const int e = blockIdx.z;
  const int count = cnt[e];
  const int rb = blockIdx.y;
  if (rb * 128 >= count) return;
  const int slot0 = off[e] + rb * 128;
  const int mlim = ((count + 63) & ~63) - rb * 128;
  const int nb = blockIdx.x;                       // 0..63

  __shared__ __align__(16) short As[128 * 64];     // 16KB [row][slot]
  __shared__ __align__(16) short Bs[128 * 64];     // 16KB

  const int tid = threadIdx.x;
  const int l = tid & 63, w = tid >> 6;
  const int wr = w >> 1, wc = w & 1;

  const int srow = l >> 3;
  const int sch  = (l & 7) ^ srow;
  const short* aptr[4];
  const short* bptr[4];
  unsigned sdst[4];
#pragma unroll
  for (int i = 0; i < 4; ++i) {
    const int q = w * 4 + i;
    const int row = q * 8 + srow;
    int tok = slot_token[slot0 + row]; if (tok < 0) tok = 0;
    aptr[i] = hsb + (size_t)tok * kH + sch * 8;
    bptr[i] = w13t + ((size_t)e * 8192 + nb * 128 + row) * kH + sch * 8;
    sdst[i] = (unsigned)(q * 1024 + l * 16);
  }

  f32x4 acc[4][4];
#pragma unroll
  for (int mi = 0; mi < 4; ++mi)
#pragma unroll
    for (int ni = 0; ni < 4; ++ni)
#pragma unroll
      for (int r = 0; r < 4; ++r) acc[mi][ni][r] = 0.f;

  const int r16 = l & 15, g = l >> 4;

  for (int t = 0; t < kH / 64; ++t) {
    const int k0 = t * 64;
#pragma unroll
    for (int i = 0; i < 4; ++i) {
      gload16(aptr[i] + k0, (char*)As + sdst[i]);
      gload16(bptr[i] + k0, (char*)Bs + sdst[i]);
    }
    __syncthreads();
#pragma unroll
    for (int kk = 0; kk < 2; ++kk) {
      const int chunk = kk * 4 + g;
      bf16x8 af[4], bf[4];
#pragma unroll
      for (int mi = 0; mi < 4; ++mi) {
        const int m = wr * 64 + mi * 16 + r16;
        af[mi] = *(const bf16x8*)((const char*)As + m * 128 + ((chunk ^ (m & 7)) * 16));
      }
#pragma unroll
      for (int ni = 0; ni < 4; ++ni) {
        const int n = wc * 64 + ni * 16 + r16;
        bf[ni] = *(const bf16x8*)((const char*)Bs + n * 128 + ((chunk ^ (n & 7)) * 16));
      }
#pragma unroll
      for (int mi = 0; mi < 4; ++mi)
#pragma unroll
        for (int ni = 0; ni < 4; ++ni)
          acc[mi][ni] = __builtin_amdgcn_mfma_f32_16x16x32_bf16(
              af[mi], bf[ni], acc[mi][ni], 0, 0, 0);
    }
    __syncthreads();
  }

  // epilogue: cols (nb*2+wc)*32 + {0..31}; ni in {0,1}=h1, {2,3}=h3
  const int colb = (nb * 2 + wc) * 32;
#pragma unroll
  for (int mi = 0; mi < 4; ++mi)
#pragma unroll
    for (int r = 0; r < 4; ++r) {
      const int m = wr * 64 + mi * 16 + g * 4 + r;
      if (m < mlim) {
#pragma unroll
        for (int ni = 0; ni < 2; ++ni) {
          float h1 = acc[mi][ni][r];
          float h3 = acc[mi][ni + 2][r];
          float y = h1 / (1.f + expf(-h1)) * h3;
          inter[(size_t)(slot0 + m) * kI + colb + ni * 16 + r16] = f2bf(y);
        }
      }
    }
}

// --------- GEMM2: slot_out = w_slot * (inter @ w2), split-K=2, 16x16 --------
__global__ __launch_bounds__(256, 3) void g2_kernel(
    const short* __restrict__ inter, const short* __restrict__ w2t,
    const int* __restrict__ cnt, const int* __restrict__ off,
    const float* __restrict__ slot_weight, float* __restrict__ slot_out) {
  const int zz = blockIdx.z;
  const int e = zz & 7, half = zz >> 3;
  const int count = cnt[e];
  const int rb = blockIdx.y;
  if (rb * 128 >= count) return;
  const int slot0 = off[e] + rb * 128;
  const int mlim = ((count + 63) & ~63) - rb * 128;
  const int nb = blockIdx.x;                       // 0..7
  const int kbase = half * (kI / 2);

  __shared__ __align__(16) short As[128 * 64];
  __shared__ __align__(16) short Bs[128 * 64];

  const int tid = threadIdx.x;
  const int l = tid & 63, w = tid >> 6;
  const int wr = w >> 1, wc = w & 1;

  const int srow = l >> 3;
  const int sch  = (l & 7) ^ srow;
  const short* aptr[4];
  const short* bptr[4];
  unsigned sdst[4];
#pragma unroll
  for (int i = 0; i < 4; ++i) {
    const int q = w * 4 + i;
    const int row = q * 8 + srow;
    int sr = slot0 + row; if (sr >= kMaxSlots) sr = kMaxSlots - 1;
    aptr[i] = inter + (size_t)sr * kI + kbase + sch * 8;
    bptr[i] = w2t + ((size_t)e * kH + nb * 128 + row) * kI + kbase + sch * 8;
    sdst[i] = (unsigned)(q * 1024 + l * 16);
  }

  f32x4 acc[4][4];
#pragma unroll
  for (int mi = 0; mi < 4; ++mi)
#pragma unroll
    for (int ni = 0; ni < 4; ++ni)
#pragma unroll
      for (int r = 0; r < 4; ++r) acc[mi][ni][r] = 0.f;

  const int r16 = l & 15, g = l >> 4;

  for (int t = 0; t < (kI / 2) / 64; ++t) {
    const int k0 = t * 64;
#pragma unroll
    for (int i = 0; i < 4; ++i) {
      gload16(aptr[i] + k0, (char*)As + sdst[i]);
      gload16(bptr[i] + k0, (char*)Bs + sdst[i]);
    }
    __syncthreads();
#pragma unroll
    for (int kk = 0; kk < 2; ++kk) {
      const int chunk = kk * 4 + g;
      bf16x8 af[4], bf[4];
#pragma unroll
      for (int mi = 0; mi < 4; ++mi) {
        const int m = wr * 64 + mi * 16 + r16;
        af[mi] = *(const bf16x8*)((const char*)As + m * 128 + ((chunk ^ (m & 7)) * 16));
      }
#pragma unroll
      for (int ni = 0; ni < 4; ++ni) {
        const int n = wc * 64 + ni * 16 + r16;
        bf[ni] = *(const bf16x8*)((const char*)Bs + n * 128 + ((chunk ^ (n & 7)) * 16));
      }
#pragma unroll
      for (int mi = 0; mi < 4; ++mi)
#pragma unroll
        for (int ni = 0; ni < 4; ++ni)
          acc[mi][ni] = __builtin_amdgcn_mfma_f32_16x16x32_bf16(
              af[mi], bf[ni], acc[mi][ni], 0, 0, 0);
    }
    __syncthreads();
  }

#pragma unroll
  for (int mi = 0; mi < 4; ++mi)
#pragma unroll
    for (int r = 0; r < 4; ++r) {
      const int m = wr * 64 + mi * 16 + g * 4 + r;
      if (m < mlim) {
        const float sw = slot_weight[slot0 + m];
        const size_t orow = ((size_t)half * kMaxSlots + slot0 + m) * kH;
#pragma unroll
        for (int ni = 0; ni < 4; ++ni)
          slot_out[orow + nb * 128 + wc * 64 + ni * 16 + r16] =
              sw * acc[mi][ni][r];
      }
    }
}

// ------- combine -------------------------------------------------------------
__global__ __launch_bounds__(256) void combine4_kernel(
    const float* __restrict__ slot_out, const int* __restrict__ token_slots,
    float* __restrict__ out) {
  int idx = blockIdx.x * 256 + threadIdx.x;
  int t = idx >> 8;
  int c = (idx & 255) * 4;
  int s0 = token_slots[t * 2];
  int s1 = token_slots[t * 2 + 1];
  const size_t HS = (size_t)kMaxSlots * kH;
  float4 a = *(const float4*)(slot_out + (size_t)s0 * kH + c);
  float4 b = *(const float4*)(slot_out + (size_t)s1 * kH + c);
  float4 a2 = *(const float4*)(slot_out + HS + (size_t)s0 * kH + c);
  float4 b2 = *(const float4*)(slot_out + HS + (size_t)s1 * kH + c);
  float4 o;
  o.x = a.x + b.x + a2.x + b2.x; o.y = a.y + b.y + a2.y + b2.y;
  o.z = a.z + b.z + a2.z + b2.z; o.w = a.w + b.w + a2.w + b2.w;
  *(float4*)(out + (size_t)t * kH + c) = o;
}

// ===================== fallback path (r1, in-loop convert) ==================
__global__ __launch_bounds__(256) void fb_mlp1(
    const float* __restrict__ hs,
    const float* __restrict__ w1s, const float* __restrict__ w3s,
    const int* __restrict__ cnt, const int* __restrict__ off,
    const int* __restrict__ slot_token, short* __restrict__ inter) {
  const int e = blockIdx.z;
  const int count = cnt[e];
  const int rb = blockIdx.y;
  if (rb * 64 >= count) return;
  const int slot0 = off[e] + rb * 64;
  const int nb = blockIdx.x * 128;
  __shared__ __align__(16) short As[4 * 64 * 8];
  __shared__ __align__(16) short Bs[2][4 * 128 * 8];
  const int tid  = threadIdx.x;
  const int lane = tid & 63;
  const int wid  = tid >> 6;
  const int wr = wid >> 1, wc = wid & 1;
  const int am = tid & 63, akb = tid >> 6;
  int tok = slot_token[slot0 + am];
  if (tok < 0) tok = 0;
  const float* arow = hs + (size_t)tok * kH + akb * 8;
  const int which = tid >> 7;
  const int bn0 = (tid & 31) * 4;
  const int bkb = (tid >> 5) & 3;
  const float* wbase = (which ? w3s : w1s) +
      (size_t)e * kH * kI + (size_t)(bkb * 8) * kI + nb + bn0;
  char* bdstp = (char*)&Bs[which][0];
  f32x4 acc[2][2][4];
#pragma unroll
  for (int s = 0; s < 2; ++s)
#pragma unroll
    for (int mi = 0; mi < 2; ++mi)
#pragma unroll
      for (int ni = 0; ni < 4; ++ni)
#pragma unroll
        for (int r = 0; r < 4; ++r) acc[s][mi][ni][r] = 0.f;
  const int g = lane >> 4, r16 = lane & 15;
  for (int k0 = 0; k0 < kH; k0 += 32) {
    float4 a0 = *(const float4*)(arow + k0);
    float4 a1 = *(const float4*)(arow + k0 + 4);
    bf16x8 av;
    av[0] = f2bf(a0.x); av[1] = f2bf(a0.y); av[2] = f2bf(a0.z); av[3] = f2bf(a0.w);
    av[4] = f2bf(a1.x); av[5] = f2bf(a1.y); av[6] = f2bf(a1.z); av[7] = f2bf(a1.w);
    *(bf16x8*)&As[(akb * 64 + am) * 8] = av;
    {
      const float* bp = wbase + (size_t)k0 * kI;
      float4 v[8];
#pragma unroll
      for (int j = 0; j < 8; ++j) v[j] = *(const float4*)(bp + (size_t)j * kI);
      const float* vf = (const float*)v;
#pragma unroll
      for (int i = 0; i < 4; ++i) {
        bf16x8 w;
#pragma unroll
        for (int j = 0; j < 8; ++j) w[j] = f2bf(vf[j * 4 + i]);
        int n = bn0 + i;
        unsigned ba = (unsigned)((bkb * 128 + n) * 16) ^ ((((unsigned)n >> 3) & 7u) << 4);
        *(bf16x8*)(bdstp + ba) = w;
      }
    }
    __syncthreads();
    bf16x8 af[2], bfr[2][4];
#pragma unroll
    for (int mi = 0; mi < 2; ++mi)
      af[mi] = *(const bf16x8*)&As[(g * 64 + wr * 32 + mi * 16 + r16) * 8];
#pragma unroll
    for (int s = 0; s < 2; ++s)
#pragma unroll
      for (int ni = 0; ni < 4; ++ni) {
        int n = wc * 64 + ni * 16 + r16;
        unsigned ba = (unsigned)((g * 128 + n) * 16) ^ ((((unsigned)n >> 3) & 7u) << 4);
        bfr[s][ni] = *(const bf16x8*)((char*)&Bs[s][0] + ba);
      }
#pragma unroll
    for (int s = 0; s < 2; ++s)
#pragma unroll
      for (int mi = 0; mi < 2; ++mi)
#pragma unroll
        for (int ni = 0; ni < 4; ++ni)
          acc[s][mi][ni] = __builtin_amdgcn_mfma_f32_16x16x32_bf16(
              af[mi], bfr[s][ni], acc[s][mi][ni], 0, 0, 0);
    __syncthreads();
  }
#pragma unroll
  for (int mi = 0; mi < 2; ++mi)
#pragma unroll
    for (int ni = 0; ni < 4; ++ni)
#pragma unroll
      for (int r = 0; r < 4; ++r) {
        float h1 = acc[0][mi][ni][r];
        float h3 = acc[1][mi][ni][r];
        float y = h1 / (1.f + expf(-h1)) * h3;
        int m = wr * 32 + mi * 16 + g * 4 + r;
        int n = nb + wc * 64 + ni * 16 + r16;
        inter[(size_t)(slot0 + m) * kI + n] = f2bf(y);
      }
}

__global__ __launch_bounds__(256) void fb_mlp2(
    const short* __restrict__ inter, const float* __restrict__ w2s,
    const int* __restrict__ cnt, const int* __restrict__ off,
    const float* __restrict__ slot_weight, float* __restrict__ slot_out) {
  const int e = blockIdx.z;
  const int count = cnt[e];
  const int rb = blockIdx.y;
  if (rb * 64 >= count) return;
  const int slot0 = off[e] + rb * 64;
  const int nb = blockIdx.x * 128;
  __shared__ __align__(16) short As[8 * 64 * 8];
  __shared__ __align__(16) short Bs[8 * 128 * 8];
  const int tid  = threadIdx.x;
  const int lane = tid & 63;
  const int wid  = tid >> 6;
  const int wr = wid >> 1, wc = wid & 1;
  const int am = tid & 63, akb = tid >> 6;
  const short* arow = inter + (size_t)(slot0 + am) * kI;
  const int bn0 = (tid & 31) * 4;
  const int bkb = tid >> 5;
  const float* wbase = w2s + (size_t)e * kI * kH + (size_t)(bkb * 8) * kH + nb + bn0;
  f32x4 acc[2][4];
#pragma unroll
  for (int mi = 0; mi < 2; ++mi)
#pragma unroll
    for (int ni = 0; ni < 4; ++ni)
#pragma unroll
      for (int r = 0; r < 4; ++r) acc[mi][ni][r] = 0.f;
  const int g = lane >> 4, r16 = lane & 15;
  for (int k0 = 0; k0 < kI; k0 += 64) {
    bf16x8 x0 = *(const bf16x8*)(arow + k0 + akb * 8);
    bf16x8 x1 = *(const bf16x8*)(arow + k0 + (akb + 4) * 8);
    *(bf16x8*)&As[(akb * 64 + am) * 8] = x0;
    *(bf16x8*)&As[((akb + 4) * 64 + am) * 8] = x1;
    {
      const float* bp = wbase + (size_t)k0 * kH;
      float4 v[8];
#pragma unroll
      for (int j = 0; j < 8; ++j) v[j] = *(const float4*)(bp + (size_t)j * kH);
      const float* vf = (const float*)v;
#pragma unroll
      for (int i = 0; i < 4; ++i) {
        bf16x8 w;
#pragma unroll
        for (int j = 0; j < 8; ++j) w[j] = f2bf(vf[j * 4 + i]);
        int n = bn0 + i;
        unsigned ba = (unsigned)((bkb * 128 + n) * 16) ^ ((((unsigned)n >> 3) & 7u) << 4);
        *(bf16x8*)((char*)&Bs[0] + ba) = w;
      }
    }
    __syncthreads();
#pragma unroll
    for (int kk = 0; kk < 2; ++kk) {
      bf16x8 af[2], bfr[4];
#pragma unroll
      for (int mi = 0; mi < 2; ++mi)
        af[mi] = *(const bf16x8*)&As[((kk * 4 + g) * 64 + wr * 32 + mi * 16 + r16) * 8];
#pragma unroll
      for (int ni = 0; ni < 4; ++ni) {
        int n = wc * 64 + ni * 16 + r16;
        unsigned ba = (unsigned)(((kk * 4 + g) * 128 + n) * 16) ^ ((((unsigned)n >> 3) & 7u) << 4);
        bfr[ni] = *(const bf16x8*)((char*)&Bs[0] + ba);
      }
#pragma unroll
      for (int mi = 0; mi < 2; ++mi)
#pragma unroll
        for (int ni = 0; ni < 4; ++ni)
          acc[mi][ni] = __builtin_amdgcn_mfma_f32_16x16x32_bf16(
              af[mi], bfr[ni], acc[mi][ni], 0, 0, 0);
    }
    __syncthreads();
  }
  float sw[2][4];
#pragma unroll
  for (int mi = 0; mi < 2; ++mi)
#pragma unroll
    for (int r = 0; r < 4; ++r)
      sw[mi][r] = slot_weight[slot0 + wr * 32 + mi * 16 + g * 4 + r];
#pragma unroll
  for (int mi = 0; mi < 2; ++mi)
#pragma unroll
    for (int ni = 0; ni < 4; ++ni)
#pragma unroll
      for (int r = 0; r < 4; ++r) {
        int m = wr * 32 + mi * 16 + g * 4 + r;
        int n = nb + wc * 64 + ni * 16 + r16;
        slot_out[(size_t)(slot0 + m) * kH + n] = sw[mi][r] * acc[mi][ni][r];
      }
}

__global__ __launch_bounds__(256) void fb_combine(
    const float* __restrict__ slot_out, const int* __restrict__ token_slots,
    float* __restrict__ out) {
  int idx = blockIdx.x * 256 + threadIdx.x;
  int t = idx >> 8;
  int c = (idx & 255) * 4;
  int s0 = token_slots[t * 2];
  int s1 = token_slots[t * 2 + 1];
  float4 a = *(const float4*)(slot_out + (size_t)s0 * kH + c);
  float4 b = *(const float4*)(slot_out + (size_t)s1 * kH + c);
  float4 o;
  o.x = a.x + b.x; o.y = a.y + b.y; o.z = a.z + b.z; o.w = a.w + b.w;
  *(float4*)(out + (size_t)t * kH + c) = o;
}

// ============================== launcher ====================================
extern "C" void kernel_launch(void* const* d_in, const int* in_sizes, int n_in,
                              void* d_out, int out_size, void* d_ws, size_t ws_size,
                              hipStream_t stream) {
  (void)in_sizes; (void)n_in; (void)out_size;
  const float* hs  = (const float*)d_in[0];
  const float* gw  = (const float*)d_in[1];
  const float* w1s = (const float*)d_in[2];
  const float* w2s = (const float*)d_in[3];
  const float* w3s = (const float*)d_in[4];
  float* out = (float*)d_out;
  char* ws = (char*)d_ws;

  // shared control region
  int*   cnt         = (int*)(ws + 0);
  int*   cursor      = (int*)(ws + 64);
  int*   off         = (int*)(ws + 128);
  int*   tok_e       = (int*)(ws + 256);
  float* tok_w       = (float*)(ws + 16640);
  int*   token_slots = (int*)(ws + 33024);
  int*   slot_token  = (int*)(ws + 49408);
  float* slot_weight = (float*)(ws + 68352);

  // prep-path layout (overlaid; NEED = 176,291,840 B, same as r2-r4)
  constexpr size_t OFF_HSB     = 131072;
  constexpr size_t OFF_W13T    = OFF_HSB + (size_t)kT * kH * 2;     // 4,325,376
  constexpr size_t SZ_W13T     = (size_t)kNE * 8192 * kH * 2;       // 134,217,728
  constexpr size_t OFF_INTER   = OFF_W13T + SZ_W13T;                // 138,543,104
  constexpr size_t SZ_INTER    = (size_t)kMaxSlots * kI * 2;        // 37,748,736
  constexpr size_t NEED        = OFF_INTER + SZ_INTER;              // 176,291,840
  constexpr size_t OFF_W2T     = OFF_W13T;                          // overlay after g1
  constexpr size_t OFF_SLOTOUT = OFF_W13T + (size_t)kNE * kH * kI * 2; // 71,434,240

  hipMemsetAsync(ws, 0, 256, stream);
  router_kernel<<<kT / 4, 256, 0, stream>>>(hs, gw, cnt, tok_e, tok_w);
  offsets_kernel<<<1, 256, 0, stream>>>(cnt, off, slot_token, slot_weight);
  assign_kernel<<<kT / 256, 256, 0, stream>>>(tok_e, tok_w, off, cursor,
                                              slot_token, slot_weight, token_slots);

  if (ws_size >= NEED) {
    short* hsb      = (short*)(ws + OFF_HSB);
    short* w13t     = (short*)(ws + OFF_W13T);
    short* w2t      = (short*)(ws + OFF_W2T);
    short* inter    = (short*)(ws + OFF_INTER);
    float* slot_out = (float*)(ws + OFF_SLOTOUT);

    conv_hs_kernel<<<(kT * kH / 8) / 256, 256, 0, stream>>>(hs, hsb);
    tconv_v2<0><<<dim3(256, 1, 16), 256, 0, stream>>>(w1s, w3s, w13t);
    g1_kernel<<<dim3(8192 / 128, kT / 128, kNE), 256, 0, stream>>>(
        hsb, w13t, cnt, off, slot_token, inter);
    tconv_v2<1><<<dim3(256, 1, 8), 256, 0, stream>>>(w2s, nullptr, w2t);
    g2_kernel<<<dim3(kH / 128, kT / 128, kNE * 2), 256, 0, stream>>>(
        inter, w2t, cnt, off, slot_weight, slot_out);
    combine4_kernel<<<(kT * kH / 4) / 256, 256, 0, stream>>>(slot_out, token_slots, out);
  } else {
    // fallback: r1 layout
    float* slot_out = (float*)(ws + 131072);
    short* inter    = (short*)(ws + 131072 + 18874368);
    fb_mlp1<<<dim3(kI / 128, kT / 64, kNE), 256, 0, stream>>>(
        hs, w1s, w3s, cnt, off, slot_token, inter);
    fb_mlp2<<<dim3(kH / 128, kT / 64, kNE), 256, 0, stream>>>(
        inter, w2s, cnt, off, slot_weight, slot_out);
    fb_combine<<<(kT * kH / 4) / 256, 256, 0, stream>>>(slot_out, token_slots, out);
  }
}